// Round 6
// baseline (10827.455 us; speedup 1.0000x reference)
//
#include <hip/hip_runtime.h>

// T=512, B=32, I=512, H=512, bidirectional GRU, fp32.
// Round-6: 2-blocks/CU co-residency, LDS-budget-aware.
//   Main kernel: 512 blocks = 2 dirs x 256 j-pair slices (2 j's each, full
//   batch). Weights 12x512 f32 = 24KB LDS/block -> occupancy calc grants
//   2 blocks/CU even under a 64KB shared-mem budget (round-5 48.25KB/block
//   likely tripped hipErrorCooperativeLaunchTooLarge at 512 blocks; the
//   error was swallowed -> kernel never ran -> absmax 4.125 = max|h0|).
//   d = bid>>8: HW dispatch pairs bids {c, c+256} on one CU -> opposite
//   directions co-resident -> independent chains, stalls overlap.
//   Fallback: if the coop launch is rejected, run the verbatim round-4
//   kernel (256 blocks, known-good 3.85ms). Deterministic branch ->
//   graph-capture-safe.
// Sync unchanged: per-block monotonic step-flags (64B lines, no RMW),
// write-through publishes (sc0 sc1 -> L3), x-partials hide the round trip.

constexpr int T_ = 512, B_ = 32, I_ = 512, H_ = 512;
constexpr int NTHR = 512;
constexpr int ROW_F4 = 128;          // 512 floats per LDS weight row
constexpr int FLAG_STRIDE = 16;      // dwords; 64B per flag line

typedef float f32x4 __attribute__((ext_vector_type(4)));
typedef float f32x2 __attribute__((ext_vector_type(2)));

__device__ __forceinline__ float sigmoid_(float v) {
    return 1.0f / (1.0f + __expf(-v));
}
__device__ __forceinline__ float tanh_(float v) {
    v = fminf(fmaxf(v, -15.0f), 15.0f);
    float e = __expf(2.0f * v);
    return (e - 1.0f) / (e + 1.0f);
}

// ================== main kernel: 512 blocks, 24KB LDS ==================
// tid = [jj(1) | bs(4) | q(4)]: q = K-sixteenth, bs = batch pair, jj = which
// of the block's 2 j's (uniform per wave). 2 batch rows per thread.
__global__ __launch_bounds__(NTHR, 4) void gru_main(
    const float* __restrict__ x, const float* __restrict__ h0,
    const float* __restrict__ w_ih, const float* __restrict__ w_hh,
    const float* __restrict__ b_ih, const float* __restrict__ b_hh,
    float* __restrict__ out, unsigned* __restrict__ flags)
{
    extern __shared__ float lds[];           // 12x512 weights + 64 gather
    float4* lds4 = (float4*)lds;
    float*  ldsh = lds + 12 * 512;           // h gather buffer (64 floats)

    const int bid = blockIdx.x;
    const int d   = bid >> 8;                // 0=fwd (bids 0-255), 1=bwd
    const int s2  = bid & 255;               // j-pair slice: j in {2s2, 2s2+1}
    const int tid = threadIdx.x;

    // ---- stage the slice's 12 weight rows into LDS (one-time) ----
    // row = m*2 + jjr ; m: 0..2 = w_ih r,z,n ; 3..5 = w_hh r,z,n
    for (int idx = tid; idx < 12 * ROW_F4; idx += NTHR) {
        const int row = idx >> 7;
        const int f4p = idx & 127;
        const int m   = row >> 1, jjr = row & 1;
        const int g   = (m < 3) ? m : m - 3;
        const float* W = (m < 3) ? w_ih : w_hh;
        const float4* src =
            (const float4*)(W + ((size_t)d * (3 * H_) + g * H_ + s2 * 2 + jjr) * (size_t)I_);
        lds4[row * ROW_F4 + f4p] = src[f4p];
    }
    __syncthreads();

    const int q  = tid & 15;
    const int bs = (tid >> 4) & 15;
    const int jj = tid >> 8;                 // uniform per wave
    const int b0 = bs * 2;                   // this thread's 2 batch rows
    const int j  = s2 * 2 + jj;              // output h-index

    const float bihr = b_ih[d * 1536 + j];
    const float bihz = b_ih[d * 1536 + 512 + j];
    const float bihn = b_ih[d * 1536 + 1024 + j];
    const float bhhr = b_hh[d * 1536 + j];
    const float bhhz = b_hh[d * 1536 + 512 + j];
    const float bhhn = b_hh[d * 1536 + 1024 + j];

    const float4* wri = lds4 + (0 * 2 + jj) * ROW_F4 + q;
    const float4* wzi = lds4 + (2 + jj) * ROW_F4 + q;
    const float4* wni = lds4 + (4 + jj) * ROW_F4 + q;
    const float4* wrh = lds4 + (6 + jj) * ROW_F4 + q;
    const float4* wzh = lds4 + (8 + jj) * ROW_F4 + q;
    const float4* wnh = lds4 + (10 + jj) * ROW_F4 + q;

    unsigned* flagchain = flags + (size_t)d * 256 * FLAG_STRIDE;

    float xar[2], xaz[2], xan[2];
    auto xpart = [&](int t) {
#pragma unroll
        for (int bi = 0; bi < 2; ++bi) { xar[bi] = 0.f; xaz[bi] = 0.f; xan[bi] = 0.f; }
        const float4* xr0 = (const float4*)(x + ((size_t)t * B_ + b0) * I_) + q;
        const float4* xr1 = (const float4*)(x + ((size_t)t * B_ + b0 + 1) * I_) + q;
#pragma unroll
        for (int i = 0; i < 8; ++i) {
            const int o = i * 16;
            const float4 w0 = wri[o], w1 = wzi[o], w2 = wni[o];
            const float4 xv0 = xr0[o], xv1 = xr1[o];
            xar[0] = fmaf(w0.x, xv0.x, fmaf(w0.y, xv0.y, fmaf(w0.z, xv0.z, fmaf(w0.w, xv0.w, xar[0]))));
            xaz[0] = fmaf(w1.x, xv0.x, fmaf(w1.y, xv0.y, fmaf(w1.z, xv0.z, fmaf(w1.w, xv0.w, xaz[0]))));
            xan[0] = fmaf(w2.x, xv0.x, fmaf(w2.y, xv0.y, fmaf(w2.z, xv0.z, fmaf(w2.w, xv0.w, xan[0]))));
            xar[1] = fmaf(w0.x, xv1.x, fmaf(w0.y, xv1.y, fmaf(w0.z, xv1.z, fmaf(w0.w, xv1.w, xar[1]))));
            xaz[1] = fmaf(w1.x, xv1.x, fmaf(w1.y, xv1.y, fmaf(w1.z, xv1.z, fmaf(w1.w, xv1.w, xaz[1]))));
            xan[1] = fmaf(w2.x, xv1.x, fmaf(w2.y, xv1.y, fmaf(w2.z, xv1.z, fmaf(w2.w, xv1.w, xan[1]))));
        }
    };

    xpart(d ? T_ - 1 : 0);

    for (int k = 0; k < T_; ++k) {
        const int t = d ? (T_ - 1 - k) : k;

        // ---- wait for h_{k-1}: wave 0 polls this chain's 256 flags ----
        if (k > 0 && tid < 64) {
            const unsigned tgt = (unsigned)k;
            unsigned* f0 = flagchain + tid * FLAG_STRIDE;
            unsigned* f1 = f0 + 64 * FLAG_STRIDE;
            unsigned* f2 = f0 + 128 * FLAG_STRIDE;
            unsigned* f3 = f0 + 192 * FLAG_STRIDE;
            for (;;) {
                const unsigned a = __hip_atomic_load(f0, __ATOMIC_RELAXED, __HIP_MEMORY_SCOPE_AGENT);
                const unsigned b = __hip_atomic_load(f1, __ATOMIC_RELAXED, __HIP_MEMORY_SCOPE_AGENT);
                const unsigned c = __hip_atomic_load(f2, __ATOMIC_RELAXED, __HIP_MEMORY_SCOPE_AGENT);
                const unsigned e = __hip_atomic_load(f3, __ATOMIC_RELAXED, __HIP_MEMORY_SCOPE_AGENT);
                if (__all(a >= tgt && b >= tgt && c >= tgt && e >= tgt)) break;
                __builtin_amdgcn_s_sleep(1);
            }
        }
        __syncthreads();                     // A: h_{k-1} visible to all waves

        const float* hbase;
        int hstride, hoff;
        if (k == 0) {
            hbase = h0 + (size_t)d * B_ * H_; hstride = H_; hoff = 0;
        } else {
            const int tp = d ? (t + 1) : (t - 1);
            hbase = out + (size_t)tp * B_ * (2 * H_); hstride = 2 * H_; hoff = d * H_;
        }

        float hp0 = hbase[(size_t)b0 * hstride + hoff + j];
        float hp1 = hbase[(size_t)(b0 + 1) * hstride + hoff + j];

        float ahr[2], ahz[2], ahn[2];
#pragma unroll
        for (int bi = 0; bi < 2; ++bi) { ahr[bi] = 0.f; ahz[bi] = 0.f; ahn[bi] = 0.f; }
        const float4* hr0 = (const float4*)(hbase + (size_t)b0 * hstride + hoff) + q;
        const float4* hr1 = (const float4*)(hbase + (size_t)(b0 + 1) * hstride + hoff) + q;
#pragma unroll
        for (int i = 0; i < 8; ++i) {
            const int o = i * 16;
            const float4 w3 = wrh[o], w4 = wzh[o], w5 = wnh[o];
            const float4 hv0 = hr0[o], hv1 = hr1[o];
            ahr[0] = fmaf(w3.x, hv0.x, fmaf(w3.y, hv0.y, fmaf(w3.z, hv0.z, fmaf(w3.w, hv0.w, ahr[0]))));
            ahz[0] = fmaf(w4.x, hv0.x, fmaf(w4.y, hv0.y, fmaf(w4.z, hv0.z, fmaf(w4.w, hv0.w, ahz[0]))));
            ahn[0] = fmaf(w5.x, hv0.x, fmaf(w5.y, hv0.y, fmaf(w5.z, hv0.z, fmaf(w5.w, hv0.w, ahn[0]))));
            ahr[1] = fmaf(w3.x, hv1.x, fmaf(w3.y, hv1.y, fmaf(w3.z, hv1.z, fmaf(w3.w, hv1.w, ahr[1]))));
            ahz[1] = fmaf(w4.x, hv1.x, fmaf(w4.y, hv1.y, fmaf(w4.z, hv1.z, fmaf(w4.w, hv1.w, ahz[1]))));
            ahn[1] = fmaf(w5.x, hv1.x, fmaf(w5.y, hv1.y, fmaf(w5.z, hv1.z, fmaf(w5.w, hv1.w, ahn[1]))));
        }

#pragma unroll
        for (int bi = 0; bi < 2; ++bi) {
            float ar = xar[bi] + ahr[bi];
            float az = xaz[bi] + ahz[bi];
            float an = xan[bi];
            float ah = ahn[bi];
#pragma unroll
            for (int m = 1; m < 16; m <<= 1) {
                ar += __shfl_xor(ar, m);
                az += __shfl_xor(az, m);
                an += __shfl_xor(an, m);
                ah += __shfl_xor(ah, m);
            }
            const float hp = bi ? hp1 : hp0;
            const float r = sigmoid_(ar + bihr + bhhr);
            const float z = sigmoid_(az + bihz + bhhz);
            const float n = tanh_(an + bihn + r * (ah + bhhn));
            const float hnew = (1.0f - z) * n + z * hp;
            if (q == 0) ldsh[(b0 + bi) * 2 + jj] = hnew;
        }
        __syncthreads();                     // B: gather buffer complete

        // ---- publish h_k: 32 coalesced write-through dwordx2 ----
        if (tid < 64) {
            if (tid < 32) {
                const f32x2 hv2 = *(const f32x2*)&ldsh[tid * 2];
                float* dst = out + ((size_t)t * B_ + tid) * (2 * H_) + d * H_ + s2 * 2;
                asm volatile("global_store_dwordx2 %0, %1, off sc0 sc1"
                             :: "v"(dst), "v"(hv2) : "memory");
                if (k == T_ - 1) {
                    float* hn = out + (size_t)T_ * B_ * (2 * H_)
                              + ((size_t)d * B_ + tid) * H_ + s2 * 2;
                    *(f32x2*)hn = hv2;
                }
            }
            asm volatile("s_waitcnt vmcnt(0)" ::: "memory");
            if (tid == 0)
                __hip_atomic_store(flagchain + s2 * FLAG_STRIDE, (unsigned)(k + 1),
                                   __ATOMIC_RELAXED, __HIP_MEMORY_SCOPE_AGENT);
        }

        if (k + 1 < T_) xpart(d ? (T_ - 2 - k) : (k + 1));
    }
}

// ============ fallback: verbatim round-4 kernel (known-good) ============
__global__ __launch_bounds__(NTHR, 1) void gru_fb(
    const float* __restrict__ x, const float* __restrict__ h0,
    const float* __restrict__ w_ih, const float* __restrict__ w_hh,
    const float* __restrict__ b_ih, const float* __restrict__ b_hh,
    float* __restrict__ out, unsigned* __restrict__ flags)
{
    extern __shared__ float lds[];
    float4* lds4 = (float4*)lds;
    float*  ldsh = lds + 24 * 512;

    const int bid = blockIdx.x;
    const int d   = bid >> 7;
    const int s   = bid & 127;
    const int tid = threadIdx.x;

    for (int idx = tid; idx < 24 * ROW_F4; idx += NTHR) {
        const int row = idx >> 7;
        const int f4p = idx & 127;
        const int m   = row >> 2, jjr = row & 3;
        const int g   = (m < 3) ? m : m - 3;
        const float* W = (m < 3) ? w_ih : w_hh;
        const float4* src =
            (const float4*)(W + ((size_t)d * (3 * H_) + g * H_ + s * 4 + jjr) * (size_t)I_);
        lds4[row * ROW_F4 + f4p] = src[f4p];
    }
    __syncthreads();

    const int q     = tid & 15;
    const int bglow = (tid >> 4) & 3;
    const int upper = tid >> 6;
    const int jj    = upper & 3;
    const int bgh   = upper >> 2;
    const int b0    = bgh * 16 + bglow * 4;
    const int j     = s * 4 + jj;

    const float bihr = b_ih[d * 1536 + j];
    const float bihz = b_ih[d * 1536 + 512 + j];
    const float bihn = b_ih[d * 1536 + 1024 + j];
    const float bhhr = b_hh[d * 1536 + j];
    const float bhhz = b_hh[d * 1536 + 512 + j];
    const float bhhn = b_hh[d * 1536 + 1024 + j];

    const float4* wri = lds4 + (0 * 4 + jj) * ROW_F4 + q;
    const float4* wzi = lds4 + (1 * 4 + jj) * ROW_F4 + q;
    const float4* wni = lds4 + (2 * 4 + jj) * ROW_F4 + q;
    const float4* wrh = lds4 + (3 * 4 + jj) * ROW_F4 + q;
    const float4* wzh = lds4 + (4 * 4 + jj) * ROW_F4 + q;
    const float4* wnh = lds4 + (5 * 4 + jj) * ROW_F4 + q;

    unsigned* flagdir = flags + d * 128 * FLAG_STRIDE;

    float xar[4], xaz[4], xan[4];
    auto xpart = [&](int t) {
#pragma unroll
        for (int bi = 0; bi < 4; ++bi) { xar[bi] = 0.f; xaz[bi] = 0.f; xan[bi] = 0.f; }
        const float4* xr[4];
#pragma unroll
        for (int bi = 0; bi < 4; ++bi)
            xr[bi] = (const float4*)(x + ((size_t)t * B_ + (b0 + bi)) * I_) + q;
#pragma unroll 2
        for (int i = 0; i < 8; ++i) {
            const int o = i * 16;
            const float4 w0 = wri[o], w1 = wzi[o], w2 = wni[o];
#pragma unroll
            for (int bi = 0; bi < 4; ++bi) {
                const float4 xv = xr[bi][o];
                xar[bi] = fmaf(w0.x, xv.x, fmaf(w0.y, xv.y, fmaf(w0.z, xv.z, fmaf(w0.w, xv.w, xar[bi]))));
                xaz[bi] = fmaf(w1.x, xv.x, fmaf(w1.y, xv.y, fmaf(w1.z, xv.z, fmaf(w1.w, xv.w, xaz[bi]))));
                xan[bi] = fmaf(w2.x, xv.x, fmaf(w2.y, xv.y, fmaf(w2.z, xv.z, fmaf(w2.w, xv.w, xan[bi]))));
            }
        }
    };

    xpart(d ? T_ - 1 : 0);

    for (int k = 0; k < T_; ++k) {
        const int t = d ? (T_ - 1 - k) : k;

        if (k > 0 && tid < 64) {
            const unsigned tgt = (unsigned)k;
            unsigned* f0 = flagdir + tid * FLAG_STRIDE;
            unsigned* f1 = flagdir + (64 + tid) * FLAG_STRIDE;
            for (;;) {
                const unsigned a = __hip_atomic_load(f0, __ATOMIC_RELAXED, __HIP_MEMORY_SCOPE_AGENT);
                const unsigned b = __hip_atomic_load(f1, __ATOMIC_RELAXED, __HIP_MEMORY_SCOPE_AGENT);
                if (__all(a >= tgt && b >= tgt)) break;
                __builtin_amdgcn_s_sleep(1);
            }
        }
        __syncthreads();

        const float* hbase;
        int hstride, hoff;
        if (k == 0) {
            hbase = h0 + (size_t)d * B_ * H_; hstride = H_; hoff = 0;
        } else {
            const int tp = d ? (t + 1) : (t - 1);
            hbase = out + (size_t)tp * B_ * (2 * H_); hstride = 2 * H_; hoff = d * H_;
        }

        float hp[4];
#pragma unroll
        for (int bi = 0; bi < 4; ++bi)
            hp[bi] = hbase[(size_t)(b0 + bi) * hstride + hoff + j];

        float ahr[4], ahz[4], ahn[4];
#pragma unroll
        for (int bi = 0; bi < 4; ++bi) { ahr[bi] = 0.f; ahz[bi] = 0.f; ahn[bi] = 0.f; }
        const float4* hr[4];
#pragma unroll
        for (int bi = 0; bi < 4; ++bi)
            hr[bi] = (const float4*)(hbase + (size_t)(b0 + bi) * hstride + hoff) + q;
#pragma unroll 2
        for (int i = 0; i < 8; ++i) {
            const int o = i * 16;
            const float4 w3 = wrh[o], w4 = wzh[o], w5 = wnh[o];
#pragma unroll
            for (int bi = 0; bi < 4; ++bi) {
                const float4 hv = hr[bi][o];
                ahr[bi] = fmaf(w3.x, hv.x, fmaf(w3.y, hv.y, fmaf(w3.z, hv.z, fmaf(w3.w, hv.w, ahr[bi]))));
                ahz[bi] = fmaf(w4.x, hv.x, fmaf(w4.y, hv.y, fmaf(w4.z, hv.z, fmaf(w4.w, hv.w, ahz[bi]))));
                ahn[bi] = fmaf(w5.x, hv.x, fmaf(w5.y, hv.y, fmaf(w5.z, hv.z, fmaf(w5.w, hv.w, ahn[bi]))));
            }
        }

#pragma unroll
        for (int bi = 0; bi < 4; ++bi) {
            float ar = xar[bi] + ahr[bi];
            float az = xaz[bi] + ahz[bi];
            float an = xan[bi];
            float ah = ahn[bi];
#pragma unroll
            for (int m = 1; m < 16; m <<= 1) {
                ar += __shfl_xor(ar, m);
                az += __shfl_xor(az, m);
                an += __shfl_xor(an, m);
                ah += __shfl_xor(ah, m);
            }
            const float r = sigmoid_(ar + bihr + bhhr);
            const float z = sigmoid_(az + bihz + bhhz);
            const float n = tanh_(an + bihn + r * (ah + bhhn));
            const float hnew = (1.0f - z) * n + z * hp[bi];
            if (q == 0) ldsh[(b0 + bi) * 4 + jj] = hnew;
        }
        __syncthreads();

        if (tid < 64) {
            if (tid < 32) {
                const f32x4 hv4 = *(const f32x4*)&ldsh[tid * 4];
                float* dst = out + ((size_t)t * B_ + tid) * (2 * H_) + d * H_ + s * 4;
                asm volatile("global_store_dwordx4 %0, %1, off sc0 sc1"
                             :: "v"(dst), "v"(hv4) : "memory");
                if (k == T_ - 1) {
                    float* hn = out + (size_t)T_ * B_ * (2 * H_)
                              + ((size_t)d * B_ + tid) * H_ + s * 4;
                    *(f32x4*)hn = hv4;
                }
            }
            asm volatile("s_waitcnt vmcnt(0)" ::: "memory");
            if (tid == 0)
                __hip_atomic_store(flagdir + s * FLAG_STRIDE, (unsigned)(k + 1),
                                   __ATOMIC_RELAXED, __HIP_MEMORY_SCOPE_AGENT);
        }

        if (k + 1 < T_) xpart(d ? (T_ - 2 - k) : (k + 1));
    }
}

extern "C" void kernel_launch(void* const* d_in, const int* in_sizes, int n_in,
                              void* d_out, int out_size, void* d_ws, size_t ws_size,
                              hipStream_t stream) {
    const float* x    = (const float*)d_in[0];
    const float* h0   = (const float*)d_in[1];
    const float* w_ih = (const float*)d_in[2];
    const float* w_hh = (const float*)d_in[3];
    const float* b_ih = (const float*)d_in[4];
    const float* b_hh = (const float*)d_in[5];
    float* out = (float*)d_out;
    unsigned* flags = (unsigned*)d_ws;

    // zero 2 x 256 flag lines (covers both kernels' layouts)
    (void)hipMemsetAsync(d_ws, 0, 2 * 256 * FLAG_STRIDE * sizeof(unsigned), stream);

    void* args[] = { (void*)&x, (void*)&h0, (void*)&w_ih, (void*)&w_hh,
                     (void*)&b_ih, (void*)&b_hh, (void*)&out, (void*)&flags };

    const unsigned shmem_main = (12 * 512 + 64) * sizeof(float);   // ~24.3 KiB
    hipError_t err = hipLaunchCooperativeKernel((void*)gru_main, dim3(512), dim3(NTHR),
                                                args, shmem_main, stream);
    if (err != hipSuccess) {
        // deterministic geometry -> same branch every call (graph-safe)
        const unsigned shmem_fb = (24 * 512 + 128) * sizeof(float); // ~48.5 KiB
        (void)hipLaunchCooperativeKernel((void*)gru_fb, dim3(256), dim3(NTHR),
                                         args, shmem_fb, stream);
    }
}